// Round 1
// baseline (247.080 us; speedup 1.0000x reference)
//
#include <hip/hip_runtime.h>

#define TLEN     6000
#define NV4      1500        // float4 groups per series
#define CHUNK_V4 256         // float4 per chunk = 1024 elements
#define HALF_V4  768         // float4 per half-series = 3 chunks
#define EPS      1e-6f
#define LN_EPS   (-13.815511f) // ln(1e-6)
#define INV_EPS  1e6f

__device__ __forceinline__ float pcen_full(float xv, float M, float alpha,
                                           float delta, float r, float deltar) {
    float gain = __expf(-alpha * (LN_EPS + __logf(fmaf(M, INV_EPS, 1.0f))));
    return __powf(fmaf(xv, gain, delta), r) - deltar;
}

// b^e for integer e in [0,63] — safe for any b
__device__ __forceinline__ float ipow6(float b, int e) {
    float r = 1.0f;
    #pragma unroll
    for (int i = 0; i < 6; ++i) {
        if (e & 1) r *= b;
        b *= b;
        e >>= 1;
    }
    return r;
}

// Process one 1024-element chunk held in q[0..3] (16 contiguous elems per lane,
// lanes in time order). Returns the smoother carry entering the NEXT chunk
// (meaningful only when !PARTIAL — a partial chunk is always the series tail).
// Geometry note: with TLEN=6000 every in-bounds lane is FULL (16 elems), so the
// per-lane decay is the constant omsP and the scan degenerates to a
// constant-coefficient Kogge-Stone (6 shuffles instead of 12, no A-scan).
template<bool PARTIAL>
__device__ __forceinline__ float chunk_compute(
    const float4 (&q)[4], const int fb, const int lane, const bool finit,
    const float s, const float oms, const float omsP, const float Apow,
    const float A64, const bool triv,
    const float la, const float ld, const float lr,
    const float Mc, float4* __restrict__ ob)
{
    // per-lane affine offset B of the recurrence M <- oms*M + coeff*x
    float B = 0.0f;
    #pragma unroll
    for (int j = 0; j < 4; ++j) {
        if (!PARTIAL || (fb + j < NV4)) {
            const float c0 = (finit && lane == 0 && j == 0) ? 1.0f : s;
            B = fmaf(oms, B, c0 * q[j].x);
            B = fmaf(oms, B, s  * q[j].y);
            B = fmaf(oms, B, s  * q[j].z);
            B = fmaf(oms, B, s  * q[j].w);
        }
    }

    // inclusive scan: S_l = sum_{k<=l} omsP^(l-k) * B_k
    float S = B;
    float w = omsP;
    #pragma unroll
    for (int off = 1; off < 64; off <<= 1) {
        const float Sp = __shfl_up(S, off, 64);
        if (lane >= off) S = fmaf(w, Sp, S);
        w *= w;
    }
    const float Se  = __shfl_up(S, 1, 64);
    const float Be  = (lane == 0) ? 0.0f : Se;
    const float Min = fmaf(Apow, Mc, Be);   // smoother entering this lane's block

    float McNext = 0.0f;
    if (!PARTIAL) McNext = fmaf(A64, Mc, __shfl(S, 63, 64)); // exact carry

    // epilogue: rerun the recurrence seeded with Min (no Bv/pw arrays needed)
    float m = Min;
    if (triv) {
        // alpha=delta=r=1  =>  out = x / (eps + M)
        #pragma unroll
        for (int j = 0; j < 4; ++j) {
            if (!PARTIAL || (fb + j < NV4)) {
                const float c0 = (finit && lane == 0 && j == 0) ? 1.0f : s;
                float4 o;
                m = fmaf(oms, m, c0 * q[j].x); o.x = q[j].x * __builtin_amdgcn_rcpf(m + EPS);
                m = fmaf(oms, m, s  * q[j].y); o.y = q[j].y * __builtin_amdgcn_rcpf(m + EPS);
                m = fmaf(oms, m, s  * q[j].z); o.z = q[j].z * __builtin_amdgcn_rcpf(m + EPS);
                m = fmaf(oms, m, s  * q[j].w); o.w = q[j].w * __builtin_amdgcn_rcpf(m + EPS);
                ob[fb + j] = o;
            }
        }
    } else {
        const float alpha  = __expf(la);
        const float delta  = __expf(ld);
        const float r      = __expf(lr);
        const float deltar = __powf(delta, lr == 0.0f ? 1.0f : r);
        #pragma unroll
        for (int j = 0; j < 4; ++j) {
            if (!PARTIAL || (fb + j < NV4)) {
                const float c0 = (finit && lane == 0 && j == 0) ? 1.0f : s;
                float4 o;
                m = fmaf(oms, m, c0 * q[j].x); o.x = pcen_full(q[j].x, m, alpha, delta, r, deltar);
                m = fmaf(oms, m, s  * q[j].y); o.y = pcen_full(q[j].y, m, alpha, delta, r, deltar);
                m = fmaf(oms, m, s  * q[j].z); o.z = pcen_full(q[j].z, m, alpha, delta, r, deltar);
                m = fmaf(oms, m, s  * q[j].w); o.w = pcen_full(q[j].w, m, alpha, delta, r, deltar);
                ob[fb + j] = o;
            }
        }
    }
    return McNext;
}

// One wave per HALF-series (3 chunks, exact carry through the wave).
// Warm-up read only at the 3072-element boundary (h==1).
__global__ __launch_bounds__(256, 8) void pcen_kernel(
    const float* __restrict__ x,
    const float* __restrict__ log_s,
    const float* __restrict__ log_alpha,
    const float* __restrict__ log_delta,
    const float* __restrict__ log_r,
    float* __restrict__ out,
    int num_series, int F)
{
    const int g    = (int)((blockIdx.x * blockDim.x + threadIdx.x) >> 6);
    const int lane = (int)(threadIdx.x & 63);
    if (g >= num_series * 2) return;
    const int series = g >> 1;
    const int h      = g & 1;          // which half of the series
    const int f      = series % F;

    const float la = log_alpha[f], ld = log_delta[f], lr = log_r[f];
    const bool  triv = (la == 0.0f) && (ld == 0.0f) && (lr == 0.0f);

    const float s    = __expf(log_s[f]);
    const float oms  = 1.0f - s;
    const float oms2 = oms * oms;
    const float oms4 = oms2 * oms2;
    const float oms8 = oms4 * oms4;
    const float omsP = oms8 * oms8;    // oms^16 = full-lane decay

    // A64 = omsP^64 = oms^1024 = full-chunk decay
    float A64 = omsP;
    #pragma unroll
    for (int i = 0; i < 6; ++i) A64 *= A64;
    const bool decay_ok = fabsf(A64) < 1e-7f;   // one warm chunk reconstructs carry

    const float Apow = ipow6(omsP, lane);       // omsP^lane, reused every chunk

    const float4* __restrict__ xb = (const float4*)(x + (size_t)series * TLEN);
    float4* __restrict__ ob       = (float4*)(out + (size_t)series * TLEN);

    const int hb = h * HALF_V4;    // first float4 of this half
    const int l4 = 4 * lane;

    float4 bufA[4], bufB[4];

    // ---- issue chunk-0 loads immediately (always fully in-bounds) ----
    #pragma unroll
    for (int j = 0; j < 4; ++j) bufA[j] = xb[hb + l4 + j];

    // ---- half-boundary warm-up (h==1 only) ----
    float Mc = 0.0f;
    if (h == 1) {
        const float wl = ipow6(omsP, 63 - lane);   // weight for lane partial sums
        if (decay_ok) {
            // single warm chunk: elements [2048, 3072)
            #pragma unroll
            for (int j = 0; j < 4; ++j) bufB[j] = xb[(HALF_V4 - CHUNK_V4) + l4 + j];
            float Bw = 0.0f;
            #pragma unroll
            for (int j = 0; j < 4; ++j) {
                const float4 qw = bufB[j];
                Bw = fmaf(oms, Bw, s * qw.x);
                Bw = fmaf(oms, Bw, s * qw.y);
                Bw = fmaf(oms, Bw, s * qw.z);
                Bw = fmaf(oms, Bw, s * qw.w);
            }
            float v = wl * Bw;
            #pragma unroll
            for (int off = 1; off < 64; off <<= 1) v += __shfl_xor(v, off, 64);
            Mc = v;
        } else {
            // exact fallback: accumulate the entire first half
            for (int wc = 0; wc < 3; ++wc) {
                float Bw = 0.0f;
                #pragma unroll
                for (int j = 0; j < 4; ++j) {
                    const float4 qw = xb[wc * CHUNK_V4 + l4 + j];
                    const float c0 = (wc == 0 && lane == 0 && j == 0) ? 1.0f : s;
                    Bw = fmaf(oms, Bw, c0 * qw.x);
                    Bw = fmaf(oms, Bw, s  * qw.y);
                    Bw = fmaf(oms, Bw, s  * qw.z);
                    Bw = fmaf(oms, Bw, s  * qw.w);
                }
                float v = wl * Bw;
                #pragma unroll
                for (int off = 1; off < 64; off <<= 1) v += __shfl_xor(v, off, 64);
                Mc = fmaf(A64, Mc, v);
            }
        }
    }

    // ---- chunk pipeline: prefetch next while computing current ----
    // prefetch chunk 1 (always fully in-bounds: max idx 1279 < 1500)
    #pragma unroll
    for (int j = 0; j < 4; ++j) bufB[j] = xb[hb + CHUNK_V4 + l4 + j];

    // compute chunk 0
    Mc = chunk_compute<false>(bufA, hb + l4, lane, (h == 0),
                              s, oms, omsP, Apow, A64, triv, la, ld, lr, Mc, ob);

    // prefetch chunk 2 (partial for h==1: elements [5120,6000))
    {
        const int fb2 = hb + 2 * CHUNK_V4 + l4;
        #pragma unroll
        for (int j = 0; j < 4; ++j)
            bufA[j] = (fb2 + j < NV4) ? xb[fb2 + j] : make_float4(0.f, 0.f, 0.f, 0.f);
    }

    // compute chunk 1
    Mc = chunk_compute<false>(bufB, hb + CHUNK_V4 + l4, lane, false,
                              s, oms, omsP, Apow, A64, triv, la, ld, lr, Mc, ob);

    // compute chunk 2 (tail — carry unused)
    chunk_compute<true>(bufA, hb + 2 * CHUNK_V4 + l4, lane, false,
                        s, oms, omsP, Apow, A64, triv, la, ld, lr, Mc, ob);
}

extern "C" void kernel_launch(void* const* d_in, const int* in_sizes, int n_in,
                              void* d_out, int out_size, void* d_ws, size_t ws_size,
                              hipStream_t stream) {
    const float* x         = (const float*)d_in[0];
    const float* log_s     = (const float*)d_in[1];
    const float* log_alpha = (const float*)d_in[2];
    const float* log_delta = (const float*)d_in[3];
    const float* log_r     = (const float*)d_in[4];
    float* out             = (float*)d_out;

    const int F = in_sizes[1];                  // 128 bands
    const int num_series = in_sizes[0] / TLEN;  // 4096
    const int num_waves  = num_series * 2;      // one wave per half-series
    const int num_threads = num_waves * 64;
    const int grid = (num_threads + 255) / 256;

    pcen_kernel<<<grid, 256, 0, stream>>>(x, log_s, log_alpha, log_delta, log_r,
                                          out, num_series, F);
}

// Round 2
// 191.191 us; speedup vs baseline: 1.2923x; 1.2923x over previous
//
#include <hip/hip_runtime.h>

#define TLEN     6000
#define NV4      1500        // float4 groups per series
#define CHUNK_V4 256         // float4 per chunk = 1024 elements
#define HALF_V4  768         // float4 per half-series = 3 chunks
#define EPS      1e-6f
#define LN_EPS   (-13.815511f) // ln(1e-6)
#define INV_EPS  1e6f

__device__ __forceinline__ float pcen_full(float xv, float M, float alpha,
                                           float delta, float r, float deltar) {
    float gain = __expf(-alpha * (LN_EPS + __logf(fmaf(M, INV_EPS, 1.0f))));
    return __powf(fmaf(xv, gain, delta), r) - deltar;
}

// b^e for integer e in [0,63] — safe for any b
__device__ __forceinline__ float ipow6(float b, int e) {
    float r = 1.0f;
    #pragma unroll
    for (int i = 0; i < 6; ++i) {
        if (e & 1) r *= b;
        b *= b;
        e >>= 1;
    }
    return r;
}

// Process one 1024-element chunk held in q[0..3] (16 contiguous elems per lane,
// lanes in time order). Returns the smoother carry entering the NEXT chunk
// (meaningful only when !PARTIAL — a partial chunk is always the series tail).
// With TLEN=6000 every in-bounds lane is FULL (16 elems), so the per-lane decay
// is the constant omsP and the scan degenerates to a constant-coefficient
// Kogge-Stone (6 shuffles, no A-scan).
template<bool PARTIAL>
__device__ __forceinline__ float chunk_compute(
    const float4 (&q)[4], const int fb, const int lane, const bool finit,
    const float s, const float oms, const float omsP, const float Apow,
    const float A64, const bool triv,
    const float la, const float ld, const float lr,
    const float Mc, float4* __restrict__ ob)
{
    // per-lane affine offset B of the recurrence M <- oms*M + coeff*x
    float B = 0.0f;
    #pragma unroll
    for (int j = 0; j < 4; ++j) {
        if (!PARTIAL || (fb + j < NV4)) {
            const float c0 = (finit && lane == 0 && j == 0) ? 1.0f : s;
            B = fmaf(oms, B, c0 * q[j].x);
            B = fmaf(oms, B, s  * q[j].y);
            B = fmaf(oms, B, s  * q[j].z);
            B = fmaf(oms, B, s  * q[j].w);
        }
    }

    // inclusive scan: S_l = sum_{k<=l} omsP^(l-k) * B_k
    float S = B;
    float w = omsP;
    #pragma unroll
    for (int off = 1; off < 64; off <<= 1) {
        const float Sp = __shfl_up(S, off, 64);
        if (lane >= off) S = fmaf(w, Sp, S);
        w *= w;
    }
    const float Se  = __shfl_up(S, 1, 64);
    const float Be  = (lane == 0) ? 0.0f : Se;
    const float Min = fmaf(Apow, Mc, Be);   // smoother entering this lane's block

    float McNext = 0.0f;
    if (!PARTIAL) McNext = fmaf(A64, Mc, __shfl(S, 63, 64)); // exact carry

    // epilogue: rerun the recurrence seeded with Min
    float m = Min;
    if (triv) {
        // alpha=delta=r=1  =>  out = x / (eps + M)
        #pragma unroll
        for (int j = 0; j < 4; ++j) {
            if (!PARTIAL || (fb + j < NV4)) {
                const float c0 = (finit && lane == 0 && j == 0) ? 1.0f : s;
                float4 o;
                m = fmaf(oms, m, c0 * q[j].x); o.x = q[j].x * __builtin_amdgcn_rcpf(m + EPS);
                m = fmaf(oms, m, s  * q[j].y); o.y = q[j].y * __builtin_amdgcn_rcpf(m + EPS);
                m = fmaf(oms, m, s  * q[j].z); o.z = q[j].z * __builtin_amdgcn_rcpf(m + EPS);
                m = fmaf(oms, m, s  * q[j].w); o.w = q[j].w * __builtin_amdgcn_rcpf(m + EPS);
                ob[fb + j] = o;
            }
        }
    } else {
        const float alpha  = __expf(la);
        const float delta  = __expf(ld);
        const float r      = __expf(lr);
        const float deltar = __powf(delta, lr == 0.0f ? 1.0f : r);
        #pragma unroll
        for (int j = 0; j < 4; ++j) {
            if (!PARTIAL || (fb + j < NV4)) {
                const float c0 = (finit && lane == 0 && j == 0) ? 1.0f : s;
                float4 o;
                m = fmaf(oms, m, c0 * q[j].x); o.x = pcen_full(q[j].x, m, alpha, delta, r, deltar);
                m = fmaf(oms, m, s  * q[j].y); o.y = pcen_full(q[j].y, m, alpha, delta, r, deltar);
                m = fmaf(oms, m, s  * q[j].z); o.z = pcen_full(q[j].z, m, alpha, delta, r, deltar);
                m = fmaf(oms, m, s  * q[j].w); o.w = pcen_full(q[j].w, m, alpha, delta, r, deltar);
                ob[fb + j] = o;
            }
        }
    }
    return McNext;
}

// One wave per HALF-series (3 chunks, exact carry through the wave).
// Warm-up read only at the 3072-element boundary (h==1).
// launch_bounds(256,4): 128-VGPR budget. (256,8) capped at 64 VGPRs and the
// double-buffer spilled to scratch — WRITE_SIZE 96->276 MB, VALUBusy 22->6%.
__global__ __launch_bounds__(256, 4) void pcen_kernel(
    const float* __restrict__ x,
    const float* __restrict__ log_s,
    const float* __restrict__ log_alpha,
    const float* __restrict__ log_delta,
    const float* __restrict__ log_r,
    float* __restrict__ out,
    int num_series, int F)
{
    const int g    = (int)((blockIdx.x * blockDim.x + threadIdx.x) >> 6);
    const int lane = (int)(threadIdx.x & 63);
    if (g >= num_series * 2) return;
    const int series = g >> 1;
    const int h      = g & 1;          // which half of the series
    const int f      = series % F;

    const float la = log_alpha[f], ld = log_delta[f], lr = log_r[f];
    const bool  triv = (la == 0.0f) && (ld == 0.0f) && (lr == 0.0f);

    const float s    = __expf(log_s[f]);
    const float oms  = 1.0f - s;
    const float oms2 = oms * oms;
    const float oms4 = oms2 * oms2;
    const float oms8 = oms4 * oms4;
    const float omsP = oms8 * oms8;    // oms^16 = full-lane decay

    // A64 = omsP^64 = oms^1024 = full-chunk decay
    float A64 = omsP;
    #pragma unroll
    for (int i = 0; i < 6; ++i) A64 *= A64;
    const bool decay_ok = fabsf(A64) < 1e-7f;   // one warm chunk reconstructs carry

    const float Apow = ipow6(omsP, lane);       // omsP^lane, reused every chunk

    const float4* __restrict__ xb = (const float4*)(x + (size_t)series * TLEN);
    float4* __restrict__ ob       = (float4*)(out + (size_t)series * TLEN);

    const int hb = h * HALF_V4;    // first float4 of this half
    const int l4 = 4 * lane;

    float4 bufA[4], bufB[4];

    // ---- issue chunk-0 loads immediately (always fully in-bounds) ----
    #pragma unroll
    for (int j = 0; j < 4; ++j) bufA[j] = xb[hb + l4 + j];

    // ---- half-boundary warm-up (h==1 only) ----
    float Mc = 0.0f;
    if (h == 1) {
        const float wl = ipow6(omsP, 63 - lane);   // weight for lane partial sums
        if (decay_ok) {
            // single warm chunk: elements [2048, 3072)
            #pragma unroll
            for (int j = 0; j < 4; ++j) bufB[j] = xb[(HALF_V4 - CHUNK_V4) + l4 + j];
            float Bw = 0.0f;
            #pragma unroll
            for (int j = 0; j < 4; ++j) {
                const float4 qw = bufB[j];
                Bw = fmaf(oms, Bw, s * qw.x);
                Bw = fmaf(oms, Bw, s * qw.y);
                Bw = fmaf(oms, Bw, s * qw.z);
                Bw = fmaf(oms, Bw, s * qw.w);
            }
            float v = wl * Bw;
            #pragma unroll
            for (int off = 1; off < 64; off <<= 1) v += __shfl_xor(v, off, 64);
            Mc = v;
        } else {
            // exact fallback: accumulate the entire first half
            for (int wc = 0; wc < 3; ++wc) {
                float Bw = 0.0f;
                #pragma unroll
                for (int j = 0; j < 4; ++j) {
                    const float4 qw = xb[wc * CHUNK_V4 + l4 + j];
                    const float c0 = (wc == 0 && lane == 0 && j == 0) ? 1.0f : s;
                    Bw = fmaf(oms, Bw, c0 * qw.x);
                    Bw = fmaf(oms, Bw, s  * qw.y);
                    Bw = fmaf(oms, Bw, s  * qw.z);
                    Bw = fmaf(oms, Bw, s  * qw.w);
                }
                float v = wl * Bw;
                #pragma unroll
                for (int off = 1; off < 64; off <<= 1) v += __shfl_xor(v, off, 64);
                Mc = fmaf(A64, Mc, v);
            }
        }
    }

    // ---- chunk pipeline: prefetch next while computing current ----
    // prefetch chunk 1 (always fully in-bounds: max idx 1279 < 1500)
    #pragma unroll
    for (int j = 0; j < 4; ++j) bufB[j] = xb[hb + CHUNK_V4 + l4 + j];

    // compute chunk 0
    Mc = chunk_compute<false>(bufA, hb + l4, lane, (h == 0),
                              s, oms, omsP, Apow, A64, triv, la, ld, lr, Mc, ob);

    // prefetch chunk 2 (partial for h==1: elements [5120,6000))
    {
        const int fb2 = hb + 2 * CHUNK_V4 + l4;
        #pragma unroll
        for (int j = 0; j < 4; ++j)
            bufA[j] = (fb2 + j < NV4) ? xb[fb2 + j] : make_float4(0.f, 0.f, 0.f, 0.f);
    }

    // compute chunk 1
    Mc = chunk_compute<false>(bufB, hb + CHUNK_V4 + l4, lane, false,
                              s, oms, omsP, Apow, A64, triv, la, ld, lr, Mc, ob);

    // compute chunk 2 (tail — carry unused)
    chunk_compute<true>(bufA, hb + 2 * CHUNK_V4 + l4, lane, false,
                        s, oms, omsP, Apow, A64, triv, la, ld, lr, Mc, ob);
}

extern "C" void kernel_launch(void* const* d_in, const int* in_sizes, int n_in,
                              void* d_out, int out_size, void* d_ws, size_t ws_size,
                              hipStream_t stream) {
    const float* x         = (const float*)d_in[0];
    const float* log_s     = (const float*)d_in[1];
    const float* log_alpha = (const float*)d_in[2];
    const float* log_delta = (const float*)d_in[3];
    const float* log_r     = (const float*)d_in[4];
    float* out             = (float*)d_out;

    const int F = in_sizes[1];                  // 128 bands
    const int num_series = in_sizes[0] / TLEN;  // 4096
    const int num_waves  = num_series * 2;      // one wave per half-series
    const int num_threads = num_waves * 64;
    const int grid = (num_threads + 255) / 256;

    pcen_kernel<<<grid, 256, 0, stream>>>(x, log_s, log_alpha, log_delta, log_r,
                                          out, num_series, F);
}

// Round 4
// 182.887 us; speedup vs baseline: 1.3510x; 1.0454x over previous
//
#include <hip/hip_runtime.h>

#define TLEN     6000
#define NV4      1500        // float4 groups per series
#define CHUNK_V4 256         // float4 per chunk = 1024 elements
#define SUB_V4   64          // float4 per sub-chunk = 256 elements
#define HALF_V4  768         // float4 per half-series = 3 chunks
#define EPS      1e-6f
#define LN_EPS   (-13.815511f) // ln(1e-6)
#define INV_EPS  1e6f

__device__ __forceinline__ float pcen_full(float xv, float M, float alpha,
                                           float delta, float r, float deltar) {
    float gain = __expf(-alpha * (LN_EPS + __logf(fmaf(M, INV_EPS, 1.0f))));
    return __powf(fmaf(xv, gain, delta), r) - deltar;
}

// b^e for integer e in [0,63] — safe for any b
__device__ __forceinline__ float ipow6(float b, int e) {
    float r = 1.0f;
    #pragma unroll
    for (int i = 0; i < 6; ++i) {
        if (e & 1) r *= b;
        b *= b;
        e >>= 1;
    }
    return r;
}

// One 1024-elem chunk in INTERLEAVED layout: q[j] = xb[cb + 64*j + lane].
// Sub-chunk j (256 elems): lane L owns times [256j + 4L, 256j + 4L + 4) —
// lanes in time order within each sub-chunk, 4 elems per lane, so per-lane
// decay is the constant oms4 and the scan is a constant-coefficient
// Kogge-Stone. All global accesses are lane-contiguous (1 KB / instr).
// Returns the smoother carry entering the next chunk (PARTIAL = tail, unused).
template<bool PARTIAL>
__device__ __forceinline__ float chunk_compute(
    const float4 (&q)[4], const int cb, const int lane, const bool finit,
    const float s, const float oms, const float oms4, const float Apow4,
    const float A256, const bool triv,
    const float alpha, const float delta, const float r, const float deltar,
    float Mc, float4* __restrict__ ob)
{
    // 4 independent per-lane affine offsets (coefficient c0=1 only at t=0)
    float B[4];
    #pragma unroll
    for (int j = 0; j < 4; ++j) {
        const float c0 = (finit && j == 0 && lane == 0) ? 1.0f : s;
        float b = c0 * q[j].x;
        b = fmaf(oms, b, s * q[j].y);
        b = fmaf(oms, b, s * q[j].z);
        b = fmaf(oms, b, s * q[j].w);
        B[j] = b;
    }

    // 4 independent Kogge-Stone scans, interleaved per level (hides DS latency)
    float S[4];
    #pragma unroll
    for (int j = 0; j < 4; ++j) S[j] = B[j];
    float w = oms4;
    #pragma unroll
    for (int off = 1; off < 64; off <<= 1) {
        #pragma unroll
        for (int j = 0; j < 4; ++j) {
            const float Sp = __shfl_up(S[j], off, 64);
            if (lane >= off) S[j] = fmaf(w, Sp, S[j]);
        }
        w *= w;
    }

    // entering value per sub-chunk + serial carry across sub-chunks
    float Min[4];
    #pragma unroll
    for (int j = 0; j < 4; ++j) {
        const float Se = __shfl_up(S[j], 1, 64);
        const float Be = (lane == 0) ? 0.0f : Se;
        Min[j] = fmaf(Apow4, Mc, Be);                 // decay oms^(4*lane) from sub start
        Mc = fmaf(A256, Mc, __shfl(S[j], 63, 64));    // exact sub-chunk carry
    }

    // epilogue: rerun recurrence seeded with Min[j]
    if (triv) {
        // alpha=delta=r=1  =>  out = x / (eps + M)
        #pragma unroll
        for (int j = 0; j < 4; ++j) {
            const int vi = cb + SUB_V4 * j + lane;
            if (!PARTIAL || vi < NV4) {
                const float c0 = (finit && j == 0 && lane == 0) ? 1.0f : s;
                float m = Min[j]; float4 o;
                m = fmaf(oms, m, c0 * q[j].x); o.x = q[j].x * __builtin_amdgcn_rcpf(m + EPS);
                m = fmaf(oms, m, s  * q[j].y); o.y = q[j].y * __builtin_amdgcn_rcpf(m + EPS);
                m = fmaf(oms, m, s  * q[j].z); o.z = q[j].z * __builtin_amdgcn_rcpf(m + EPS);
                m = fmaf(oms, m, s  * q[j].w); o.w = q[j].w * __builtin_amdgcn_rcpf(m + EPS);
                ob[vi] = o;
            }
        }
    } else {
        #pragma unroll
        for (int j = 0; j < 4; ++j) {
            const int vi = cb + SUB_V4 * j + lane;
            if (!PARTIAL || vi < NV4) {
                const float c0 = (finit && j == 0 && lane == 0) ? 1.0f : s;
                float m = Min[j]; float4 o;
                m = fmaf(oms, m, c0 * q[j].x); o.x = pcen_full(q[j].x, m, alpha, delta, r, deltar);
                m = fmaf(oms, m, s  * q[j].y); o.y = pcen_full(q[j].y, m, alpha, delta, r, deltar);
                m = fmaf(oms, m, s  * q[j].z); o.z = pcen_full(q[j].z, m, alpha, delta, r, deltar);
                m = fmaf(oms, m, s  * q[j].w); o.w = pcen_full(q[j].w, m, alpha, delta, r, deltar);
                ob[vi] = o;
            }
        }
    }
    return Mc;
}

// One wave per HALF-series (3 chunks, exact carry through the wave).
// launch_bounds(256,4): 128-VGPR budget — (256,8) forced a spill (r1:
// WRITE_SIZE 96->276 MB, VALUBusy 22->6%). Keep 4.
__global__ __launch_bounds__(256, 4) void pcen_kernel(
    const float* __restrict__ x,
    const float* __restrict__ log_s,
    const float* __restrict__ log_alpha,
    const float* __restrict__ log_delta,
    const float* __restrict__ log_r,
    float* __restrict__ out,
    int num_series, int F)
{
    const int g    = (int)((blockIdx.x * blockDim.x + threadIdx.x) >> 6);
    const int lane = (int)(threadIdx.x & 63);
    if (g >= num_series * 2) return;
    const int series = g >> 1;
    const int h      = g & 1;          // which half of the series
    const int f      = series % F;

    const float la = log_alpha[f], ld = log_delta[f], lr = log_r[f];
    const bool  triv = (la == 0.0f) && (ld == 0.0f) && (lr == 0.0f);

    const float s    = __expf(log_s[f]);
    const float oms  = 1.0f - s;
    const float oms2 = oms * oms;
    const float oms4 = oms2 * oms2;    // per-lane (4-elem) decay

    // A256 = oms4^64 = oms^256 (sub-chunk decay); A1024 = chunk decay
    float A256 = oms4;
    #pragma unroll
    for (int i = 0; i < 6; ++i) A256 *= A256;
    float A1024 = A256 * A256; A1024 *= A1024;
    const bool decay_ok = fabsf(A1024) < 1e-7f;   // one warm chunk reconstructs carry

    const float Apow4 = ipow6(oms4, lane);        // oms4^lane, reused every sub-chunk

    // non-trivial-path params (once per wave)
    float alpha = 0.f, delta = 0.f, rr = 0.f, deltar = 0.f;
    if (!triv) {
        alpha  = __expf(la);
        delta  = __expf(ld);
        rr     = __expf(lr);
        deltar = __powf(delta, lr == 0.0f ? 1.0f : rr);
    }

    const float4* __restrict__ xb = (const float4*)(x + (size_t)series * TLEN);
    float4* __restrict__ ob       = (float4*)(out + (size_t)series * TLEN);

    const int hb = h * HALF_V4;    // first float4 of this half

    float4 bufA[4], bufB[4];

    // ---- issue chunk-0 loads immediately (coalesced, fully in-bounds) ----
    #pragma unroll
    for (int j = 0; j < 4; ++j) bufA[j] = xb[hb + SUB_V4 * j + lane];

    // ---- half-boundary warm-up (h==1 only) ----
    float Mc = 0.0f;
    if (h == 1) {
        // weight of lane L / sub j block total: oms^(1020 - 256j - 4L) = wl * A256^(3-j)
        const float wl = ipow6(oms4, 63 - lane);
        if (decay_ok) {
            // single warm chunk: elements [2048, 3072)
            #pragma unroll
            for (int j = 0; j < 4; ++j) bufB[j] = xb[(HALF_V4 - CHUNK_V4) + SUB_V4 * j + lane];
            float Bw[4];
            #pragma unroll
            for (int j = 0; j < 4; ++j) {
                float b = s * bufB[j].x;
                b = fmaf(oms, b, s * bufB[j].y);
                b = fmaf(oms, b, s * bufB[j].z);
                b = fmaf(oms, b, s * bufB[j].w);
                Bw[j] = b;
            }
            float v = wl * fmaf(A256, fmaf(A256, fmaf(A256, Bw[0], Bw[1]), Bw[2]), Bw[3]);
            #pragma unroll
            for (int off = 1; off < 64; off <<= 1) v += __shfl_xor(v, off, 64);
            Mc = v;
        } else {
            // exact fallback: accumulate the entire first half
            for (int wc = 0; wc < 3; ++wc) {
                float Bw[4];
                #pragma unroll
                for (int j = 0; j < 4; ++j) {
                    const float4 qw = xb[wc * CHUNK_V4 + SUB_V4 * j + lane];
                    const float c0 = (wc == 0 && j == 0 && lane == 0) ? 1.0f : s;
                    float b = c0 * qw.x;
                    b = fmaf(oms, b, s * qw.y);
                    b = fmaf(oms, b, s * qw.z);
                    b = fmaf(oms, b, s * qw.w);
                    Bw[j] = b;
                }
                float v = wl * fmaf(A256, fmaf(A256, fmaf(A256, Bw[0], Bw[1]), Bw[2]), Bw[3]);
                #pragma unroll
                for (int off = 1; off < 64; off <<= 1) v += __shfl_xor(v, off, 64);
                Mc = fmaf(A1024, Mc, v);
            }
        }
    }

    // ---- chunk pipeline: prefetch next while computing current ----
    // prefetch chunk 1 (always fully in-bounds)
    #pragma unroll
    for (int j = 0; j < 4; ++j) bufB[j] = xb[hb + CHUNK_V4 + SUB_V4 * j + lane];

    // compute chunk 0
    Mc = chunk_compute<false>(bufA, hb, lane, (h == 0),
                              s, oms, oms4, Apow4, A256, triv,
                              alpha, delta, rr, deltar, Mc, ob);

    // prefetch chunk 2 (partial only for h==1: elements [5120,6000))
    #pragma unroll
    for (int j = 0; j < 4; ++j) {
        const int vi = hb + 2 * CHUNK_V4 + SUB_V4 * j + lane;
        bufA[j] = (vi < NV4) ? xb[vi] : make_float4(0.f, 0.f, 0.f, 0.f);
    }

    // compute chunk 1
    Mc = chunk_compute<false>(bufB, hb + CHUNK_V4, lane, false,
                              s, oms, oms4, Apow4, A256, triv,
                              alpha, delta, rr, deltar, Mc, ob);

    // compute chunk 2 (tail — carry unused)
    chunk_compute<true>(bufA, hb + 2 * CHUNK_V4, lane, false,
                        s, oms, oms4, Apow4, A256, triv,
                        alpha, delta, rr, deltar, Mc, ob);
}

extern "C" void kernel_launch(void* const* d_in, const int* in_sizes, int n_in,
                              void* d_out, int out_size, void* d_ws, size_t ws_size,
                              hipStream_t stream) {
    const float* x         = (const float*)d_in[0];
    const float* log_s     = (const float*)d_in[1];
    const float* log_alpha = (const float*)d_in[2];
    const float* log_delta = (const float*)d_in[3];
    const float* log_r     = (const float*)d_in[4];
    float* out             = (float*)d_out;

    const int F = in_sizes[1];                  // 128 bands
    const int num_series = in_sizes[0] / TLEN;  // 4096
    const int num_waves  = num_series * 2;      // one wave per half-series
    const int num_threads = num_waves * 64;
    const int grid = (num_threads + 255) / 256;

    pcen_kernel<<<grid, 256, 0, stream>>>(x, log_s, log_alpha, log_delta, log_r,
                                          out, num_series, F);
}